// Round 4
// baseline (115.254 us; speedup 1.0000x reference)
//
#include <hip/hip_runtime.h>

// Problem constants (fixed by the reference): B=512 rows, T=32768, K=64, R=4.
#define T_LEN  32768
#define NTHR   1024      // one row per block; 32 elems/thread
#define NWAVE  (NTHR / 64)
#define KSEL   64.0f

// Native clang vector type: required by __builtin_nontemporal_load/store
// (HIP_vector_type<float,4> is a struct and is rejected). Same 16B layout.
typedef float vfloat4 __attribute__((ext_vector_type(4)));

// sigmoid via v_exp_f32 + v_rcp_f32 (~1 ulp each; verified absmax 1.5e-05 vs np ref)
__device__ __forceinline__ float fast_sigmoid(float x) {
    return __builtin_amdgcn_rcpf(1.0f + __expf(-x));
}

// a * min(2/(1+a+b), 1):  2/(1+s) >= 1  <=>  s <= 1
__device__ __forceinline__ float damp(float a, float b) {
    float s = a + b;
    float f = (s > 1.0f) ? 2.0f * __builtin_amdgcn_rcpf(1.0f + s) : 1.0f;
    return a * f;
}

// Fast-path validity: if rowmax = max(y)*scale <= 0.5 over the whole row, then for
// every pass s = y_i + y_{i+d} <= 1 => factor min(2/(1+s),1) == 1 EXACTLY, and since
// pass outputs equal pass inputs the bound holds inductively for all 4 passes.
// Then out = scale * sigmoid(scores/temp) elementwise -- no neighbor windows.
//
// Occupancy note (R2 post-mortem): launch_bounds(1024,8) -> VGPR<=64 -> 2 blocks/CU
// = 32 waves/CU (HW max). The second resident block's memory stream hides this
// block's reduction-barrier bubble. The 2-row/1-block-per-CU variant regressed
// (111.5 vs 109.2 us): co-residency beats intra-block ILP here. Do not lower the
// waves/EU bound.

__global__ __launch_bounds__(NTHR, 8)
void selector_onepass(const float* __restrict__ scores,
                      const float* __restrict__ log_temp,
                      float* __restrict__ out) {
    const int row = blockIdx.x;
    const int tid = threadIdx.x;
    const float* srow = scores + (size_t)row * T_LEN;
    float*       orow = out    + (size_t)row * T_LEN;

    float t = expf(log_temp[0]);
    const float inv_temp = 1.0f / fminf(fmaxf(t, 0.1f), 10.0f);

    // ---- Phase 1: coalesced load (lane-contiguous float4), nontemporal (read-once,
    //      no reuse to cache: inter-iteration fills evict L2/L3 anyway) ----
    const vfloat4* p4 = (const vfloat4*)srow;
    vfloat4 s[8];
    #pragma unroll
    for (int k = 0; k < 8; ++k) s[k] = __builtin_nontemporal_load(&p4[tid + NTHR * k]);

    float sum = 0.0f, mx = 0.0f;
    #pragma unroll
    for (int k = 0; k < 8; ++k) {
        s[k].x = fast_sigmoid(s[k].x * inv_temp);
        s[k].y = fast_sigmoid(s[k].y * inv_temp);
        s[k].z = fast_sigmoid(s[k].z * inv_temp);
        s[k].w = fast_sigmoid(s[k].w * inv_temp);
        sum += (s[k].x + s[k].y) + (s[k].z + s[k].w);
        mx = fmaxf(mx, fmaxf(fmaxf(s[k].x, s[k].y), fmaxf(s[k].z, s[k].w)));
    }

    // ---- Single-barrier broadcast reduction (sum + max fused) ----
    // Wave reduce, lane0 writes the wave partial, ONE barrier, then every thread
    // combines all 16 partials locally. Same-address LDS reads broadcast
    // (conflict-free); removes the second barrier + the tid0 serial section that
    // 32 resident waves would otherwise sit behind.
    #pragma unroll
    for (int off = 32; off > 0; off >>= 1) {
        sum += __shfl_down(sum, off, 64);
        mx   = fmaxf(mx, __shfl_down(mx, off, 64));
    }
    __shared__ float2 red[NWAVE];
    const int wid = tid >> 6, lane = tid & 63;
    if (lane == 0) red[wid] = make_float2(sum, mx);
    __syncthreads();
    float ts = 0.0f, tm = 0.0f;
    #pragma unroll
    for (int i = 0; i < NWAVE; ++i) {
        float2 r = red[i];
        ts += r.x;
        tm = fmaxf(tm, r.y);
    }
    const float budget = fmaxf(ts, 1e-6f);
    const float scale  = fminf(KSEL / budget, 1.0f);
    const float rowmax = tm * scale;    // block-uniform

    if (rowmax <= 0.5f) {
        // ---- Fast path (always taken for this data): out = scale * s, coalesced,
        //      nontemporal stores (write-once stream) ----
        #pragma unroll
        for (int k = 0; k < 8; ++k) {
            s[k].x *= scale; s[k].y *= scale; s[k].z *= scale; s[k].w *= scale;
        }
        if (tid == 0) s[0].x = 0.0f;   // y[:,0] = 0 (element 0 lives in lane 0, k=0)
        vfloat4* q4 = (vfloat4*)orow;
        #pragma unroll
        for (int k = 0; k < 8; ++k)
            __builtin_nontemporal_store(s[k], &q4[tid + NTHR * k]);
    } else {
        // ---- Slow path (block-uniform, correct for any input; never taken here):
        //      per-thread contiguous 2x16-output windows, re-read + damp ----
        #pragma unroll
        for (int c = 0; c < 2; ++c) {
            const int col0 = 32 * tid + 16 * c;
            float w[26];
            #pragma unroll
            for (int j = 0; j < 26; ++j)
                w[j] = fast_sigmoid(srow[(col0 + j) & (T_LEN - 1)] * inv_temp) * scale;
            #pragma unroll
            for (int j = 0; j < 25; ++j) w[j] = damp(w[j], w[j + 1]);
            #pragma unroll
            for (int j = 0; j < 23; ++j) w[j] = damp(w[j], w[j + 2]);
            #pragma unroll
            for (int j = 0; j < 20; ++j) w[j] = damp(w[j], w[j + 3]);
            #pragma unroll
            for (int j = 0; j < 16; ++j) w[j] = damp(w[j], w[j + 4]);
            if (col0 == 0) w[0] = 0.0f;
            float4* q4 = (float4*)(orow + col0);
            q4[0] = make_float4(w[0],  w[1],  w[2],  w[3]);
            q4[1] = make_float4(w[4],  w[5],  w[6],  w[7]);
            q4[2] = make_float4(w[8],  w[9],  w[10], w[11]);
            q4[3] = make_float4(w[12], w[13], w[14], w[15]);
        }
    }
}

extern "C" void kernel_launch(void* const* d_in, const int* in_sizes, int n_in,
                              void* d_out, int out_size, void* d_ws, size_t ws_size,
                              hipStream_t stream) {
    const float* scores = (const float*)d_in[0];
    const float* lt     = (const float*)d_in[1];
    float*       out    = (float*)d_out;
    const int B = in_sizes[0] / T_LEN;   // 512 rows
    selector_onepass<<<B, NTHR, 0, stream>>>(scores, lt, out);
}

// Round 5
// 108.585 us; speedup vs baseline: 1.0614x; 1.0614x over previous
//
#include <hip/hip_runtime.h>

// Problem constants (fixed by the reference): B=512 rows, T=32768, K=64, R=4.
#define T_LEN  32768
#define NTHR   1024      // one row per block; 32 elems/thread
#define KSEL   64.0f

// ============================ experiment record =============================
// R0 baseline (this kernel):            109.2 us  <-- best
// R2 two-row/block, 1 block/CU:         111.5 us  (co-residency > intra-block ILP;
//                                                  1 block/CU exposes barrier bubbles)
// R4 single-barrier red. + nontemporal: 115.3 us  (nt defeats L2 write-coalescing on
//                                                  the store stream + skips L3 load
//                                                  hits; broadcast read adds 16
//                                                  ds_reads/thread for a barrier that
//                                                  was already hidden by the 2nd
//                                                  resident block)
// Kernel ~25 us vs 134 MB naive roofline 21.3 us; pure-write fills only reach 81%
// of spec BW, mixed read+write ~85% of copy ceiling => at achievable roofline.
// ===========================================================================

// sigmoid via v_exp_f32 + v_rcp_f32 (~1 ulp each; verified absmax 1.5e-05 vs np ref)
__device__ __forceinline__ float fast_sigmoid(float x) {
    return __builtin_amdgcn_rcpf(1.0f + __expf(-x));
}

// a * min(2/(1+a+b), 1):  2/(1+s) >= 1  <=>  s <= 1
__device__ __forceinline__ float damp(float a, float b) {
    float s = a + b;
    float f = (s > 1.0f) ? 2.0f * __builtin_amdgcn_rcpf(1.0f + s) : 1.0f;
    return a * f;
}

// Fast-path validity: if max(y) <= 0.5 over the whole row, then for every pass
// s = y_i + y_{i+d} <= 1  =>  factor min(2/(1+s),1) == 1 EXACTLY, and since
// pass outputs equal pass inputs the bound holds inductively for all 4 passes.
// Then out = scale * sigmoid(scores/temp) elementwise -- no neighbor windows.

__global__ __launch_bounds__(NTHR, 8)   // VGPR<=64 -> 2 blocks/CU, 32 waves/CU (HW max)
void selector_onepass(const float* __restrict__ scores,
                      const float* __restrict__ log_temp,
                      float* __restrict__ out) {
    const int row = blockIdx.x;
    const int tid = threadIdx.x;
    const float* srow = scores + (size_t)row * T_LEN;
    float*       orow = out    + (size_t)row * T_LEN;

    float t = expf(log_temp[0]);
    const float inv_temp = 1.0f / fminf(fmaxf(t, 0.1f), 10.0f);

    // ---- Phase 1: coalesced load (lane-contiguous float4), sigmoid in place ----
    const float4* p4 = (const float4*)srow;
    float4 s[8];
    #pragma unroll
    for (int k = 0; k < 8; ++k) s[k] = p4[tid + NTHR * k];

    float sum = 0.0f, mx = 0.0f;
    #pragma unroll
    for (int k = 0; k < 8; ++k) {
        s[k].x = fast_sigmoid(s[k].x * inv_temp);
        s[k].y = fast_sigmoid(s[k].y * inv_temp);
        s[k].z = fast_sigmoid(s[k].z * inv_temp);
        s[k].w = fast_sigmoid(s[k].w * inv_temp);
        sum += (s[k].x + s[k].y) + (s[k].z + s[k].w);
        mx = fmaxf(mx, fmaxf(fmaxf(s[k].x, s[k].y), fmaxf(s[k].z, s[k].w)));
    }

    // ---- Fused block reduction: sum and max ----
    #pragma unroll
    for (int off = 32; off > 0; off >>= 1) {
        sum += __shfl_down(sum, off, 64);
        mx   = fmaxf(mx, __shfl_down(mx, off, 64));
    }
    __shared__ float redS[NTHR / 64 + 1];
    __shared__ float redM[NTHR / 64 + 1];
    const int wid = tid >> 6, lane = tid & 63;
    if (lane == 0) { redS[wid] = sum; redM[wid] = mx; }
    __syncthreads();
    if (tid == 0) {
        float ts = 0.0f, tm = 0.0f;
        #pragma unroll
        for (int i = 0; i < NTHR / 64; ++i) { ts += redS[i]; tm = fmaxf(tm, redM[i]); }
        redS[NTHR / 64] = ts;
        redM[NTHR / 64] = tm;
    }
    __syncthreads();
    const float budget = fmaxf(redS[NTHR / 64], 1e-6f);
    const float scale  = fminf(KSEL / budget, 1.0f);
    const float rowmax = redM[NTHR / 64] * scale;    // block-uniform

    if (rowmax <= 0.5f) {
        // ---- Fast path (always taken for this data): out = scale * s, coalesced ----
        #pragma unroll
        for (int k = 0; k < 8; ++k) {
            s[k].x *= scale; s[k].y *= scale; s[k].z *= scale; s[k].w *= scale;
        }
        if (tid == 0) s[0].x = 0.0f;   // y[:,0] = 0 (element 0 lives in lane 0, k=0)
        float4* q4 = (float4*)orow;
        #pragma unroll
        for (int k = 0; k < 8; ++k) q4[tid + NTHR * k] = s[k];
    } else {
        // ---- Slow path (block-uniform, correct for any input; never taken here):
        //      per-thread contiguous 2x16-output windows, re-read + damp ----
        #pragma unroll
        for (int c = 0; c < 2; ++c) {
            const int col0 = 32 * tid + 16 * c;
            float w[26];
            #pragma unroll
            for (int j = 0; j < 26; ++j)
                w[j] = fast_sigmoid(srow[(col0 + j) & (T_LEN - 1)] * inv_temp) * scale;
            #pragma unroll
            for (int j = 0; j < 25; ++j) w[j] = damp(w[j], w[j + 1]);
            #pragma unroll
            for (int j = 0; j < 23; ++j) w[j] = damp(w[j], w[j + 2]);
            #pragma unroll
            for (int j = 0; j < 20; ++j) w[j] = damp(w[j], w[j + 3]);
            #pragma unroll
            for (int j = 0; j < 16; ++j) w[j] = damp(w[j], w[j + 4]);
            if (col0 == 0) w[0] = 0.0f;
            float4* q4 = (float4*)(orow + col0);
            q4[0] = make_float4(w[0],  w[1],  w[2],  w[3]);
            q4[1] = make_float4(w[4],  w[5],  w[6],  w[7]);
            q4[2] = make_float4(w[8],  w[9],  w[10], w[11]);
            q4[3] = make_float4(w[12], w[13], w[14], w[15]);
        }
    }
}

extern "C" void kernel_launch(void* const* d_in, const int* in_sizes, int n_in,
                              void* d_out, int out_size, void* d_ws, size_t ws_size,
                              hipStream_t stream) {
    const float* scores = (const float*)d_in[0];
    const float* lt     = (const float*)d_in[1];
    float*       out    = (float*)d_out;
    const int B = in_sizes[0] / T_LEN;   // 512 rows
    selector_onepass<<<B, NTHR, 0, stream>>>(scores, lt, out);
}